// Round 1
// 1062.433 us; speedup vs baseline: 1.0934x; 1.0934x over previous
//
#include <hip/hip_runtime.h>

typedef _Float16 half_t;
typedef _Float16 h8 __attribute__((ext_vector_type(8)));
typedef _Float16 h2 __attribute__((ext_vector_type(2)));
typedef float f4 __attribute__((ext_vector_type(4)));
typedef unsigned int uint32;
typedef unsigned int u2v __attribute__((ext_vector_type(2)));

#define SHIFT16 2.772588722239781f    // log(16), fast path
#define SHIFT8  2.0794415416798357f   // log(8), fallback path
// ws float offsets:  X[64][128] | Q[64][128] | Lf[64] | Lb[64] | pad | eo16
#define WX 0
#define WQ 8192
#define WLF 16384
#define WLB 16448
#define EO_BYTE_OFF 66560u
#define FAST_WS_BYTES (EO_BYTE_OFF + 67108864u)   // eo = 4cg*4096t*64l*64B

__device__ __forceinline__ h2 pkrtz(float a, float b) {
    return __builtin_bit_cast(h2, __builtin_amdgcn_cvt_pkrtz(a, b));
}

// (a,b) <- ([a.lanes0-31 | b.lanes0-31], [a.lanes32-63 | b.lanes32-63])
__device__ __forceinline__ void swap32(uint32& a, uint32& b) {
#if __has_builtin(__builtin_amdgcn_permlane32_swap)
    u2v r = __builtin_amdgcn_permlane32_swap(a, b, false, false);
    a = r.x; b = r.y;
#else
    const uint32 pa = (uint32)__shfl_xor((int)a, 32);
    const uint32 pb = (uint32)__shfl_xor((int)b, 32);
    const bool hi = (threadIdx.x & 32) != 0;
    const uint32 na = hi ? pb : a;
    const uint32 nb = hi ? b : pa;
    a = na; b = nb;
#endif
}
// per 32-lane half: (a,b) <- ([a0-15|b0-15|a32-47|b32-47], [a16-31|b16-31|a48-63|b48-63])
__device__ __forceinline__ void swap16(uint32& a, uint32& b) {
#if __has_builtin(__builtin_amdgcn_permlane16_swap)
    u2v r = __builtin_amdgcn_permlane16_swap(a, b, false, false);
    a = r.x; b = r.y;
#else
    const uint32 sa = (uint32)__builtin_amdgcn_ds_swizzle((int)a, 0x401F);
    const uint32 sb = (uint32)__builtin_amdgcn_ds_swizzle((int)b, 0x401F);
    const bool m = (threadIdx.x & 16) != 0;
    const uint32 na = m ? sb : a;
    const uint32 nb = m ? b : sa;
    a = na; b = nb;
#endif
}

// ============================ FAST PATH =====================================

// eo16[cg][t][lane l][hd 0..15 dw]: fp16 exp(obs-SHIFT16) pairs, permuted into
// the per-lane MFMA D-layout order (lane l=q*16+n: chain n, states mt*16+q*4+r;
// dword hd=2mt+(r>>1)). LDS-staged transpose: coalesced reads AND writes.
__global__ __launch_bounds__(256)
void eo_prep(const float* __restrict__ obs, uint32* __restrict__ eo)
{
    __shared__ float sb[64 * 130];       // 64 rows (n,tl) x 128 floats, padded
    const int tid = threadIdx.x;
    const int cg = blockIdx.x >> 10;     // 4 chain-groups
    const int tb = blockIdx.x & 1023;    // 1024 blocks of 4 timesteps

    #pragma unroll
    for (int i = 0; i < 8; ++i) {        // load 64x128 floats, coalesced
        const int idx = i * 256 + tid;   // 2048 float4s
        const int row = idx >> 5, c4 = idx & 31;
        const int n = row >> 2, tl = row & 3;
        const float4 v = *(const float4*)
            &obs[((size_t)(cg * 16 + n) * 4096 + (tb * 4 + tl)) * 128 + c4 * 4];
        *(float4*)&sb[row * 130 + c4 * 4] = v;
    }
    __syncthreads();

    const int l = tid >> 2;              // output lane 0..63
    const int q = l >> 4, nn = l & 15;
    #pragma unroll
    for (int tl = 0; tl < 4; ++tl) {
        uint4 o;
        uint32* po = &o.x;
        #pragma unroll
        for (int j = 0; j < 4; ++j) {
            const int hd = (tid & 3) * 4 + j;
            const int mt = hd >> 1, rr = (hd & 1) * 2;
            const int s = mt * 16 + q * 4 + rr;
            const float* p = &sb[(nn * 4 + tl) * 130 + s];
            po[j] = __builtin_bit_cast(uint32,
                      pkrtz(__expf(p[0] - SHIFT16), __expf(p[1] - SHIFT16)));
        }
        *(uint4*)&eo[((size_t)(cg * 4096 + tb * 4 + tl) << 10) + (tid << 2)] = o;
    }
}

#define TE(N) (FW ? (N) : (4095 - (N)))

template <bool FW, int NIT>
__device__ __forceinline__ void chain(const uint32* __restrict__ eo,
                                      const float* __restrict__ trans,
                                      float* __restrict__ ws, int cg)
{
    const int l = threadIdx.x & 63;
    const int q = l >> 4, n = l & 15;
    const size_t cgbase = (size_t)cg << 22;
    const uint32* __restrict__ ebl = eo + cgbase + (l << 4);

    // exp(A) A-fragments. fwd: D = eA^T*W -> A[m][k]=eA[k][m]; bwd: A[m][k]=eA[m][k]
    h8 Af[8][4];
    #pragma unroll
    for (int mt = 0; mt < 8; ++mt)
        #pragma unroll
        for (int kc = 0; kc < 4; ++kc) {
            h8 a;
            #pragma unroll
            for (int j = 0; j < 8; ++j) {
                const int k = kc * 32 + q * 8 + j;
                const int m = mt * 16 + n;
                a[j] = (half_t)__expf(FW ? trans[k * 128 + m] : trans[m * 128 + k]);
            }
            Af[mt][kc] = a;
        }

    // eo ring: 4 slots x (2 substeps x 4 uint4) = 6-substep lookahead.
    // slot of substep V is (V>>1)&3; since the body covers 8 substeps, slot
    // indices depend only on V&7 (compile-time under full unroll).
    uint4 er[32];
    #pragma unroll
    for (int v = 0; v < 6; ++v)          // prologue: substeps 0..5 -> slots 0,0,1,1,2,2
        #pragma unroll
        for (int j = 0; j < 4; ++j)
            er[((v >> 1) & 3) * 8 + (v & 1) * 4 + j] =
                *(const uint4*)(ebl + ((size_t)TE(v) << 10) + (j << 2));

    const f4 Z = {0.f, 0.f, 0.f, 0.f};   // hoisted MFMA C-init
    f4 D[8];
    #pragma unroll
    for (int mt = 0; mt < 8; ++mt) D[mt] = (f4){1.f, 1.f, 1.f, 1.f};
    float Lacc = 0.f, rs = 1.f;

    #pragma unroll 1
    for (int tt = 0; tt < 256; ++tt) {
        #pragma unroll
        for (int u = 0; u < 8; ++u) {
            const int it = tt * 8 + u;
            if ((NIT & 3) != 0 && it >= NIT) continue;   // bwd tail guard
            const int st = u & 3;

            // issue eo loads 6 substeps ahead (every other substep); the slot
            // written is never the slot consumed this substep.
            if ((u & 1) == 0) {
                const int s = ((u >> 1) + 3) & 3;
                #pragma unroll
                for (int h = 0; h < 2; ++h)
                    #pragma unroll
                    for (int j = 0; j < 4; ++j)
                        er[s * 8 + h * 4 + j] =
                            *(const uint4*)(ebl + ((size_t)TE(it + 6 + h) << 10) + (j << 2));
            }

            if (st == 0) {                 // apply pending renorm (fp32, exact)
                #pragma unroll
                for (int mt = 0; mt < 8; ++mt) D[mt] = D[mt] * rs;
            }
            if (st == 3 && it != NIT - 1) {  // measure; overlaps with loads
                f4 m01 = __builtin_elementwise_max(D[0], D[1]);
                f4 m23 = __builtin_elementwise_max(D[2], D[3]);
                f4 m45 = __builtin_elementwise_max(D[4], D[5]);
                f4 m67 = __builtin_elementwise_max(D[6], D[7]);
                f4 ma = __builtin_elementwise_max(
                            __builtin_elementwise_max(m01, m23),
                            __builtin_elementwise_max(m45, m67));
                float M = fmaxf(fmaxf(ma.x, ma.y), fmaxf(ma.z, ma.w));
                M = fmaxf(M, __shfl_xor(M, 16));
                M = fmaxf(M, __shfl_xor(M, 32));
                Lacc += __logf(M);
                rs = __builtin_amdgcn_rcpf(M);
            }

            // pack W = fp16(D) * eo  (register-resident, no LDS)
            const uint32* ep = (const uint32*)&er[((u >> 1) & 3) * 8 + (u & 1) * 4];
            uint32 Wx[8], Wy[8];
            #pragma unroll
            for (int mt = 0; mt < 8; ++mt) {
                h2 w0 = pkrtz(D[mt].x, D[mt].y) * __builtin_bit_cast(h2, ep[2 * mt]);
                h2 w1 = pkrtz(D[mt].z, D[mt].w) * __builtin_bit_cast(h2, ep[2 * mt + 1]);
                Wx[mt] = __builtin_bit_cast(uint32, w0);
                Wy[mt] = __builtin_bit_cast(uint32, w1);
            }

            // cross-lane permute D-layout -> B-fragment layout. Replaces the
            // Sb LDS bounce: per kc, permlane32_swap then permlane16_swap of
            // the (mt=2kc, mt=2kc+1) packed pairs yields B dwords directly:
            //   w=0 pair -> (d0, d2);  w=1 pair -> (d1, d3).
            h8 Bf[4];
            #pragma unroll
            for (int kc = 0; kc < 4; ++kc) {
                uint32 x0 = Wx[2 * kc], x1 = Wx[2 * kc + 1];
                uint32 y0 = Wy[2 * kc], y1 = Wy[2 * kc + 1];
                swap32(x0, x1); swap16(x0, x1);   // x0=d0, x1=d2
                swap32(y0, y1); swap16(y0, y1);   // y0=d1, y1=d3
                uint4 bv; bv.x = x0; bv.y = y0; bv.z = x1; bv.w = y1;
                Bf[kc] = __builtin_bit_cast(h8, bv);
            }

            // 32 MFMAs: 8 independent mt chains of depth 4
            #pragma unroll
            for (int mt = 0; mt < 8; ++mt) {
                f4 acc = Z;
                acc = __builtin_amdgcn_mfma_f32_16x16x32_f16(Af[mt][0], Bf[0], acc, 0, 0, 0);
                acc = __builtin_amdgcn_mfma_f32_16x16x32_f16(Af[mt][1], Bf[1], acc, 0, 0, 0);
                acc = __builtin_amdgcn_mfma_f32_16x16x32_f16(Af[mt][2], Bf[2], acc, 0, 0, 0);
                acc = __builtin_amdgcn_mfma_f32_16x16x32_f16(Af[mt][3], Bf[3], acc, 0, 0, 0);
                D[mt] = acc;
            }
        }
    }

    float* Xo = ws + (FW ? WX : WQ) + ((cg * 16 + n) << 7);
    #pragma unroll
    for (int mt = 0; mt < 8; ++mt)
        *(f4*)&Xo[mt * 16 + q * 4] = D[mt];
    if (q == 0) ws[(FW ? WLF : WLB) + cg * 16 + n] = Lacc;
}

__global__ __launch_bounds__(64, 1)
void crf_mfma(const uint32* __restrict__ eo, const float* __restrict__ trans,
              float* __restrict__ ws)
{
    const int bid = blockIdx.x;
    if (bid < 4) chain<true,  2048>(eo, trans, ws, bid);      // eo 0..2047
    else         chain<false, 2047>(eo, trans, ws, bid - 4);  // eo 4095..2049
}

// Z = sum_s X[s]*eo_2048[s]*Q[s]; out = -(log Z + Lf + Lb + 4096*SHIFT16)
__global__ __launch_bounds__(64)
void crf_comb(const float* __restrict__ obs, const float* __restrict__ ws,
              float* __restrict__ out)
{
    const int b = blockIdx.x, l = threadIdx.x;
    const int s0 = 2 * l;
    const float2 o = *(const float2*)&obs[((((size_t)b << 12) + 2048) << 7) + s0];
    const float e0 = __expf(o.x - SHIFT16), e1 = __expf(o.y - SHIFT16);
    float v = ws[WX + b * 128 + s0] * e0 * ws[WQ + b * 128 + s0]
            + ws[WX + b * 128 + s0 + 1] * e1 * ws[WQ + b * 128 + s0 + 1];
    v += __shfl_xor(v, 1);  v += __shfl_xor(v, 2);  v += __shfl_xor(v, 4);
    v += __shfl_xor(v, 8);  v += __shfl_xor(v, 16); v += __shfl_xor(v, 32);
    if (l == 0)
        out[b] = -(__logf(v) + ws[WLF + b] + ws[WLB + b] + 4096.0f * SHIFT16);
}

// ======================= FALLBACK (R3, ws too small) ========================

typedef _Float16 h2f __attribute__((ext_vector_type(2)));
#define FTILE 16
#define FNTILE 128

#if __has_builtin(__builtin_amdgcn_fdot2)
#define FDOT2(p, e, acc) __builtin_amdgcn_fdot2((p), (e), (acc), false)
#else
#define FDOT2(p, e, acc) fmaf((float)(p).x, (float)(e).x, fmaf((float)(p).y, (float)(e).y, (acc)))
#endif

__device__ __forceinline__ h2f u2h(uint32 u) { return __builtin_bit_cast(h2f, u); }
__device__ __forceinline__ uint32 f2h(float f) {
    return (uint32)__builtin_bit_cast(unsigned short, (half_t)f);
}

#define FSTEP(N0, APPLY, MEAS)  do {                                                \
    const int row_ = fw ? ((N0) & (FTILE - 1)) : ((FTILE - 1) - ((N0) & (FTILE - 1))); \
    const float2 o2_ = *(const float2*)&obsL[(((N0) >> 4) & 1) * (FTILE * 128) + (row_ << 7) + (l << 1)]; \
    float e0_ = __expf(o2_.x - SHIFT8);                                             \
    float e1_ = __expf(o2_.y - SHIFT8);                                             \
    if (APPLY) { e0_ *= rsf; e1_ *= rsf; }                                          \
    float w0_, w1_;                                                                 \
    if (fw) { w0_ = pv0; w1_ = pv1; } else { w0_ = pv0 * e0_; w1_ = pv1 * e1_; }    \
    Pl[l] = (f2h(w1_) << 16) | f2h(w0_);                                            \
    float a0_=0.f,a1_=0.f,a2_=0.f,a3_=0.f,b0_=0.f,b1_=0.f,b2_=0.f,b3_=0.f;          \
    _Pragma("unroll")                                                               \
    for (int c_ = 0; c_ < 16; ++c_) {                                               \
        const uint4 q_ = ((const uint4*)Pl)[c_];                                    \
        const h2f p0_ = u2h(q_.x), p1_ = u2h(q_.y), p2_ = u2h(q_.z), p3_ = u2h(q_.w); \
        a0_ = FDOT2(p0_, eA[4*c_+0], a0_);                                          \
        a1_ = FDOT2(p1_, eA[4*c_+1], a1_);                                          \
        a2_ = FDOT2(p2_, eA[4*c_+2], a2_);                                          \
        a3_ = FDOT2(p3_, eA[4*c_+3], a3_);                                          \
        b0_ = FDOT2(p0_, eB[4*c_+0], b0_);                                          \
        b1_ = FDOT2(p1_, eB[4*c_+1], b1_);                                          \
        b2_ = FDOT2(p2_, eB[4*c_+2], b2_);                                          \
        b3_ = FDOT2(p3_, eB[4*c_+3], b3_);                                          \
    }                                                                               \
    const float s0_ = (a0_ + a1_) + (a2_ + a3_);                                    \
    const float s1_ = (b0_ + b1_) + (b2_ + b3_);                                    \
    if (fw) { pv0 = s0_ * e0_; pv1 = s1_ * e1_; } else { pv0 = s0_; pv1 = s1_; }    \
    if (MEAS) {                                                                     \
        float m_ = fmaxf(pv0, pv1);                                                 \
        m_ = fmaxf(m_, __shfl_xor(m_, 1));                                          \
        m_ = fmaxf(m_, __shfl_xor(m_, 2));                                          \
        m_ = fmaxf(m_, __shfl_xor(m_, 4));                                          \
        m_ = fmaxf(m_, __shfl_xor(m_, 8));                                          \
        m_ = fmaxf(m_, __shfl_xor(m_, 16));                                         \
        m_ = fmaxf(m_, __shfl_xor(m_, 32));                                         \
        rsf = __builtin_amdgcn_rcpf(m_);                                            \
        Lacc += __logf(m_);                                                         \
    }                                                                               \
} while (0)

#define FLOADR(TK) do {                                                             \
    const float4* g_ = (const float4*)(obsB + (size_t)(fw ? (TK) * (FTILE * 128)    \
                                      : (4096 - FTILE * ((TK) + 1)) * 128));        \
    r0 = g_[l];       r1 = g_[l + 64];  r2 = g_[l + 128]; r3 = g_[l + 192];         \
    r4 = g_[l + 256]; r5 = g_[l + 320]; r6 = g_[l + 384]; r7 = g_[l + 448];         \
} while (0)

#define FSTORER(TK) do {                                                            \
    float4* s_ = (float4*)&obsL[((TK) & 1) * (FTILE * 128)];                        \
    s_[l] = r0;       s_[l + 64] = r1;  s_[l + 128] = r2; s_[l + 192] = r3;         \
    s_[l + 256] = r4; s_[l + 320] = r5; s_[l + 384] = r6; s_[l + 448] = r7;         \
} while (0)

__global__ __launch_bounds__(64, 1)
void crf_half_fb(const float* __restrict__ obs, const float* __restrict__ trans,
                 float* __restrict__ ws)
{
    __shared__ __align__(16) uint32 Pl[64];
    __shared__ __align__(16) float obsL[2 * FTILE * 128];

    const int l  = threadIdx.x;
    const bool fw = blockIdx.x < 64;
    const int b  = fw ? blockIdx.x : blockIdx.x - 64;
    const float* obsB = obs + (size_t)b * 4096 * 128;

    h2f eA[64], eB[64];
    if (fw) {
        const int c0 = 2 * l;
        #pragma unroll
        for (int k = 0; k < 64; ++k) {
            h2f ta, tb;
            ta.x = (half_t)__expf(trans[(2*k    ) * 128 + c0]);
            ta.y = (half_t)__expf(trans[(2*k + 1) * 128 + c0]);
            tb.x = (half_t)__expf(trans[(2*k    ) * 128 + c0 + 1]);
            tb.y = (half_t)__expf(trans[(2*k + 1) * 128 + c0 + 1]);
            eA[k] = ta; eB[k] = tb;
        }
    } else {
        const int ro0 = (2 * l) * 128, ro1 = (2 * l + 1) * 128;
        #pragma unroll
        for (int k = 0; k < 64; ++k) {
            h2f ta, tb;
            ta.x = (half_t)__expf(trans[ro0 + 2*k]);
            ta.y = (half_t)__expf(trans[ro0 + 2*k + 1]);
            tb.x = (half_t)__expf(trans[ro1 + 2*k]);
            tb.y = (half_t)__expf(trans[ro1 + 2*k + 1]);
            eA[k] = ta; eB[k] = tb;
        }
    }

    float4 r0, r1, r2, r3, r4, r5, r6, r7;
    FLOADR(0);
    FSTORER(0);
    FLOADR(1);

    float rsf = 1.f, Lacc = 0.f, pv0, pv1;

    if (fw) {
        const float2 o2 = *(const float2*)&obsL[l << 1];
        pv0 = __expf(o2.x - SHIFT8);
        pv1 = __expf(o2.y - SHIFT8);
    } else {
        pv0 = 1.f; pv1 = 1.f;
        FSTEP(0, false, false);
    }

    for (int tile = 0; tile < FNTILE; ++tile) {
        if (tile > 0) {
            FSTORER(tile);
            if (tile < FNTILE - 1) FLOADR(tile + 1);
        }
        const int nb = tile << 4;
        #pragma unroll 1
        for (int g = 0; g < 4; ++g) {
            const int n0 = nb + (g << 2);
            if (n0 > 0) FSTEP(n0, true, false);
            FSTEP(n0 + 1, false, false);
            FSTEP(n0 + 2, false, false);
            if (n0 + 3 != 2047) FSTEP(n0 + 3, false, true);
            else                FSTEP(n0 + 3, false, false);
        }
    }

    if (fw) {
        ws[b * 128 + 2*l]     = pv0;
        ws[b * 128 + 2*l + 1] = pv1;
        if (l == 0) ws[16384 + b] = Lacc;
    } else {
        ws[8192 + b * 128 + 2*l]     = pv0;
        ws[8192 + b * 128 + 2*l + 1] = pv1;
        if (l == 0) ws[16448 + b] = Lacc;
    }
}

__global__ __launch_bounds__(64)
void crf_comb_fb(const float* __restrict__ ws, float* __restrict__ out)
{
    const int b = blockIdx.x, l = threadIdx.x;
    float s = ws[b * 128 + 2*l] * ws[8192 + b * 128 + 2*l]
            + ws[b * 128 + 2*l + 1] * ws[8192 + b * 128 + 2*l + 1];
    s += __shfl_xor(s, 1);  s += __shfl_xor(s, 2);  s += __shfl_xor(s, 4);
    s += __shfl_xor(s, 8);  s += __shfl_xor(s, 16); s += __shfl_xor(s, 32);
    if (l == 0)
        out[b] = -(__logf(s) + ws[16384 + b] + ws[16448 + b] + 4096.0f * SHIFT8);
}

// ============================================================================

extern "C" void kernel_launch(void* const* d_in, const int* in_sizes, int n_in,
                              void* d_out, int out_size, void* d_ws, size_t ws_size,
                              hipStream_t stream) {
    (void)in_sizes; (void)n_in; (void)out_size;
    const float* obs   = (const float*)d_in[0];   // [64, 4096, 128] fp32
    const float* trans = (const float*)d_in[1];   // [128, 128] fp32
    float* out = (float*)d_out;                   // [64] fp32
    float* ws  = (float*)d_ws;

    if (ws_size >= (size_t)FAST_WS_BYTES) {
        uint32* eo = (uint32*)((char*)d_ws + EO_BYTE_OFF);
        hipLaunchKernelGGL(eo_prep,  dim3(4096), dim3(256), 0, stream, obs, eo);
        hipLaunchKernelGGL(crf_mfma, dim3(8),    dim3(64),  0, stream, eo, trans, ws);
        hipLaunchKernelGGL(crf_comb, dim3(64),   dim3(64),  0, stream, obs, ws, out);
    } else {
        hipLaunchKernelGGL(crf_half_fb, dim3(128), dim3(64), 0, stream, obs, trans, ws);
        hipLaunchKernelGGL(crf_comb_fb, dim3(64),  dim3(64), 0, stream, ws, out);
    }
}